// Round 1
// baseline (1229.542 us; speedup 1.0000x reference)
//
#include <hip/hip_runtime.h>
#include <hip/hip_bf16.h>
#include <cstdint>
#include <cstddef>

#define TOK  8192
#define DIN  1024
#define HID  2048
#define DOUTN 1024
#define NEXP 8
#define GHID 1024

typedef __attribute__((ext_vector_type(8))) short bf16x8;
typedef __attribute__((ext_vector_type(4))) float floatx4;

__device__ __forceinline__ unsigned short f2b(float f) {
  unsigned int u = __float_as_uint(f);
  u += 0x7fffu + ((u >> 16) & 1u);
  return (unsigned short)(u >> 16);
}

__device__ __forceinline__ void async_cp16(const unsigned short* g, char* lds) {
  __builtin_amdgcn_global_load_lds(
      (const __attribute__((address_space(1))) unsigned int*)g,
      (__attribute__((address_space(3))) unsigned int*)lds, 16, 0, 0);
}

// ---------------- conversions ----------------

__global__ void cvt_x_kernel(const float* __restrict__ src,
                             unsigned short* __restrict__ dst, int n4) {
  int i = blockIdx.x * blockDim.x + threadIdx.x;
  if (i >= n4) return;
  float4 v = ((const float4*)src)[i];
  ushort4 o;
  o.x = f2b(v.x); o.y = f2b(v.y); o.z = f2b(v.z); o.w = f2b(v.w);
  ((ushort4*)dst)[i] = o;
}

// src [E][K][N] fp32 -> dst [E][N][K] bf16
__global__ void cvt_transpose_kernel(const float* __restrict__ src,
                                     unsigned short* __restrict__ dst,
                                     int K, int N) {
  __shared__ float tile[32][33];
  long e = blockIdx.z;
  src += e * (long)K * N;
  dst += e * (long)K * N;
  int n0 = blockIdx.x * 32, k0 = blockIdx.y * 32;
  int x = threadIdx.x, y = threadIdx.y;
#pragma unroll
  for (int i = 0; i < 4; i++)
    tile[y + 8 * i][x] = src[(long)(k0 + y + 8 * i) * N + n0 + x];
  __syncthreads();
#pragma unroll
  for (int i = 0; i < 4; i++)
    dst[(long)(n0 + y + 8 * i) * K + k0 + x] = f2b(tile[x][y + 8 * i]);
}

// ---------------- gating: fp32 SGEMM (hg = relu(x @ gw1 + gb1)) ----------------
// 128x128 tile, BK=8, 256 threads, 8x8 per thread (split 4+4)

__global__ __launch_bounds__(256) void gating_sgemm(
    const float* __restrict__ X, const float* __restrict__ W,
    const float* __restrict__ bias, float* __restrict__ H) {
  __shared__ float As[8][128];
  __shared__ float Bs[8][128];
  int tid = threadIdx.x;
  int bm = blockIdx.y, bn = blockIdx.x;
  int tx = tid & 15, ty = tid >> 4;

  float acc[8][8] = {};
  int arow = tid >> 1;
  int acol = (tid & 1) * 4;
  int brow = tid >> 5;
  int bcol = (tid & 31) * 4;
  const float* Xp = X + (size_t)(bm * 128 + arow) * DIN + acol;
  const float* Wp = W + (size_t)brow * GHID + bn * 128 + bcol;

  for (int k0 = 0; k0 < DIN; k0 += 8) {
    float4 av = *(const float4*)(Xp + k0);
    float4 bv = *(const float4*)(Wp + (size_t)k0 * GHID);
    __syncthreads();
    As[acol + 0][arow] = av.x;
    As[acol + 1][arow] = av.y;
    As[acol + 2][arow] = av.z;
    As[acol + 3][arow] = av.w;
    *(float4*)&Bs[brow][bcol] = bv;
    __syncthreads();
#pragma unroll
    for (int k = 0; k < 8; ++k) {
      float ar[8], br[8];
      *(float4*)&ar[0] = *(const float4*)&As[k][ty * 4];
      *(float4*)&ar[4] = *(const float4*)&As[k][64 + ty * 4];
      *(float4*)&br[0] = *(const float4*)&Bs[k][tx * 4];
      *(float4*)&br[4] = *(const float4*)&Bs[k][64 + tx * 4];
#pragma unroll
      for (int i = 0; i < 8; ++i)
#pragma unroll
        for (int j = 0; j < 8; ++j) acc[i][j] += ar[i] * br[j];
    }
  }

#pragma unroll
  for (int hn = 0; hn < 2; ++hn) {
    int c0 = bn * 128 + hn * 64 + tx * 4;
    float4 bb = *(const float4*)(bias + c0);
#pragma unroll
    for (int hm = 0; hm < 2; ++hm)
#pragma unroll
      for (int i = 0; i < 4; ++i) {
        int m = bm * 128 + hm * 64 + ty * 4 + i;
        float4 v;
        v.x = fmaxf(acc[hm * 4 + i][hn * 4 + 0] + bb.x, 0.f);
        v.y = fmaxf(acc[hm * 4 + i][hn * 4 + 1] + bb.y, 0.f);
        v.z = fmaxf(acc[hm * 4 + i][hn * 4 + 2] + bb.z, 0.f);
        v.w = fmaxf(acc[hm * 4 + i][hn * 4 + 3] + bb.w, 0.f);
        *(float4*)(H + (size_t)m * GHID + c0) = v;
      }
  }
}

// ---------------- gating: logits + top-2 + softmax ----------------
// one wave per token

__global__ void gating2_topk(const float* __restrict__ H,
                             const float* __restrict__ gw2,
                             const float* __restrict__ gb2,
                             int* __restrict__ gidx, float* __restrict__ gwt) {
  int wv = threadIdx.x >> 6, lane = threadIdx.x & 63;
  int t = blockIdx.x * 4 + wv;
  const float* hrow = H + (size_t)t * GHID;
  float acc[8] = {};
  for (int k = lane; k < GHID; k += 64) {
    float v = hrow[k];
    float4 g0 = *(const float4*)(gw2 + (size_t)k * 8);
    float4 g1 = *(const float4*)(gw2 + (size_t)k * 8 + 4);
    acc[0] += v * g0.x; acc[1] += v * g0.y; acc[2] += v * g0.z; acc[3] += v * g0.w;
    acc[4] += v * g1.x; acc[5] += v * g1.y; acc[6] += v * g1.z; acc[7] += v * g1.w;
  }
#pragma unroll
  for (int off = 32; off > 0; off >>= 1)
#pragma unroll
    for (int e = 0; e < 8; e++) acc[e] += __shfl_xor(acc[e], off);

  if (lane == 0) {
    float l[8];
#pragma unroll
    for (int e = 0; e < 8; e++) l[e] = acc[e] + gb2[e];
    int b0 = 0; float v0 = l[0];
#pragma unroll
    for (int e = 1; e < 8; e++) if (l[e] > v0) { v0 = l[e]; b0 = e; }
    int b1 = -1; float v1 = -3.4e38f;
#pragma unroll
    for (int e = 0; e < 8; e++)
      if (e != b0 && l[e] > v1) { v1 = l[e]; b1 = e; }
    float ex = expf(v1 - v0);
    float inv = 1.f / (1.f + ex);
    gidx[2 * t] = b0; gidx[2 * t + 1] = b1;
    gwt[2 * t] = inv; gwt[2 * t + 1] = ex * inv;
  }
}

// ---------------- routing: count / scan / scatter ----------------

__global__ void route_count(const int* __restrict__ gidx, int* cnt) {
  int t = blockIdx.x * blockDim.x + threadIdx.x;
  int lane = threadIdx.x & 63;
  int e0 = gidx[2 * t], e1 = gidx[2 * t + 1];
#pragma unroll 1
  for (int e = 0; e < NEXP; e++) {
    unsigned long long m0 = __ballot(e0 == e);
    if (m0 && lane == __ffsll(m0) - 1) atomicAdd(&cnt[e], (int)__popcll(m0));
    unsigned long long m1 = __ballot(e1 == e);
    if (m1 && lane == __ffsll(m1) - 1) atomicAdd(&cnt[e], (int)__popcll(m1));
  }
}

__global__ void route_scan(const int* __restrict__ cnt, int* base_, int* cur) {
  if (threadIdx.x == 0) {
    int s = 0;
    for (int e = 0; e < NEXP; e++) { base_[e] = s; cur[e] = s; s += cnt[e]; }
  }
}

__global__ void route_scatter(const int* __restrict__ gidx,
                              const float* __restrict__ gwt, int* cur,
                              int* __restrict__ rt, float* __restrict__ rw) {
  int t = blockIdx.x * blockDim.x + threadIdx.x;
  int lane = threadIdx.x & 63;
  int e0 = gidx[2 * t], e1 = gidx[2 * t + 1];
  float w0 = gwt[2 * t], w1 = gwt[2 * t + 1];
#pragma unroll 1
  for (int e = 0; e < NEXP; e++) {
#pragma unroll 1
    for (int s = 0; s < 2; s++) {
      int mye = s ? e1 : e0;
      unsigned long long m = __ballot(mye == e);
      if (m) {
        int leader = __ffsll(m) - 1;
        int bb = 0;
        if (lane == leader) bb = atomicAdd(&cur[e], (int)__popcll(m));
        bb = __shfl(bb, leader);
        if (mye == e) {
          int pos = bb + (int)__popcll(m & ((1ull << lane) - 1ull));
          rt[pos] = t;
          rw[pos] = s ? w1 : w0;
        }
      }
    }
  }
}

// ---------------- expert GEMMs (m97-style bf16 MFMA, 128x128x32) ----------------
// MODE 1: h   = relu(Xg @ w1 + b1)                   K=1024
// MODE 2: out = relu(h @ w2 + Xg @ wp + b2 + bp)     K=3072 (K-concat residual)
// MODE 3: d_out += gatew * (out @ w3 + b3)           K=2048 (atomic scatter)

template <int MODE>
__global__ __launch_bounds__(256, 2) void moe_gemm(
    const unsigned short* __restrict__ xb, const unsigned short* __restrict__ hbuf,
    const unsigned short* __restrict__ obuf, const unsigned short* __restrict__ w1t,
    const unsigned short* __restrict__ wpt, const unsigned short* __restrict__ w2t,
    const unsigned short* __restrict__ w3t, const float* __restrict__ b1,
    const float* __restrict__ b2, const float* __restrict__ bp,
    const float* __restrict__ b3, const int* __restrict__ rt,
    const float* __restrict__ rw, const int* __restrict__ cnt,
    const int* __restrict__ base, unsigned short* __restrict__ hout,
    unsigned short* __restrict__ oout, float* __restrict__ dout) {
  __shared__ __align__(16) unsigned short As[128 * 32];
  __shared__ __align__(16) unsigned short Bs[128 * 32];
  int tid = threadIdx.x;

  // map blockIdx.y -> (expert, local row tile)
  int lt = blockIdx.y;
  int e = 0, cn = 0, ok = 0;
  for (e = 0; e < NEXP; ++e) {
    int c = cnt[e];
    int nt = (c + 127) >> 7;
    if (lt < nt) { cn = c; ok = 1; break; }
    lt -= nt;
  }
  if (!ok) return;
  int be = base[e];
  int row0 = lt << 7;
  int tn = blockIdx.x << 7;

  // ---- staging setup (global_load_lds: lds = wave base + lane*16) ----
  int sr = tid >> 2;                       // row within 64-row issue
  int lchunk = (tid & 3) ^ ((sr >> 1) & 3); // XOR swizzle of 16B chunks
  int koffA = lchunk * 8;                  // element offset in 32-wide k row
  int rl0 = row0 + sr, rl1 = row0 + 64 + sr;
  int cl0 = min(rl0, cn - 1), cl1 = min(rl1, cn - 1);

  const unsigned short *a0p, *a1p, *a0q = nullptr, *a1q = nullptr;
  const unsigned short *bw0, *bw1, *bw0q = nullptr, *bw1q = nullptr;
  int KT;
  if (MODE == 1) {
    a0p = xb + (size_t)rt[be + cl0] * DIN + koffA;
    a1p = xb + (size_t)rt[be + cl1] * DIN + koffA;
    bw0 = w1t + ((size_t)e * HID + tn + sr) * DIN + koffA;
    bw1 = w1t + ((size_t)e * HID + tn + 64 + sr) * DIN + koffA;
    KT = DIN / 32;
  } else if (MODE == 2) {
    a0p = hbuf + (size_t)(be + cl0) * HID + koffA;
    a1p = hbuf + (size_t)(be + cl1) * HID + koffA;
    a0q = xb + (size_t)rt[be + cl0] * DIN + koffA;
    a1q = xb + (size_t)rt[be + cl1] * DIN + koffA;
    bw0 = w2t + (size_t)e * HID * HID + (size_t)(tn + sr) * HID + koffA;
    bw1 = w2t + (size_t)e * HID * HID + (size_t)(tn + 64 + sr) * HID + koffA;
    bw0q = wpt + (size_t)e * HID * DIN + (size_t)(tn + sr) * DIN + koffA;
    bw1q = wpt + (size_t)e * HID * DIN + (size_t)(tn + 64 + sr) * DIN + koffA;
    KT = (HID + DIN) / 32;
  } else {
    a0p = obuf + (size_t)(be + cl0) * HID + koffA;
    a1p = obuf + (size_t)(be + cl1) * HID + koffA;
    bw0 = w3t + (size_t)e * DOUTN * HID + (size_t)(tn + sr) * HID + koffA;
    bw1 = w3t + (size_t)e * DOUTN * HID + (size_t)(tn + 64 + sr) * HID + koffA;
    KT = HID / 32;
  }

  char* ldsA0 = (char*)As + (tid & 192) * 16;
  char* ldsB0 = (char*)Bs + (tid & 192) * 16;

  int lane = tid & 63, wv = tid >> 6;
  int wm = (wv >> 1) << 6, wn = (wv & 1) << 6;
  int q = lane >> 4, l15 = lane & 15;
  int abase = l15 * 64 + ((q ^ ((l15 >> 1) & 3)) << 4);
  const char* AsB = (const char*)As + wm * 64 + abase;
  const char* BsB = (const char*)Bs + wn * 64 + abase;

  floatx4 acc[4][4] = {};

  for (int kt = 0; kt < KT; ++kt) {
    int k0 = kt * 32;
    const unsigned short *pa0, *pa1, *pb0, *pb1;
    if (MODE == 2 && k0 >= HID) {
      int kk = k0 - HID;
      pa0 = a0q + kk; pa1 = a1q + kk; pb0 = bw0q + kk; pb1 = bw1q + kk;
    } else {
      pa0 = a0p + k0; pa1 = a1p + k0; pb0 = bw0 + k0; pb1 = bw1 + k0;
    }
    __syncthreads();
    async_cp16(pa0, ldsA0);
    async_cp16(pa1, ldsA0 + 4096);
    async_cp16(pb0, ldsB0);
    async_cp16(pb1, ldsB0 + 4096);
    __syncthreads();
    bf16x8 af[4], bfr[4];
#pragma unroll
    for (int i = 0; i < 4; i++) {
      af[i] = *(const bf16x8*)(AsB + i * 1024);
      bfr[i] = *(const bf16x8*)(BsB + i * 1024);
    }
#pragma unroll
    for (int mi = 0; mi < 4; mi++)
#pragma unroll
      for (int ni = 0; ni < 4; ni++)
        acc[mi][ni] = __builtin_amdgcn_mfma_f32_16x16x32_bf16(
            af[mi], bfr[ni], acc[mi][ni], 0, 0, 0);
  }

  // ---- epilogue (C/D: col=lane&15, row=quad*4+reg) ----
  int crow = row0 + wm + q * 4;
  int ccol0 = tn + wn + l15;
  if (MODE == 1) {
    const float* bb = b1 + (size_t)e * HID;
#pragma unroll
    for (int ni = 0; ni < 4; ++ni) {
      int col = ccol0 + ni * 16;
      float bias = bb[col];
#pragma unroll
      for (int mi = 0; mi < 4; ++mi)
#pragma unroll
        for (int rg = 0; rg < 4; ++rg) {
          int rr = crow + mi * 16 + rg;
          if (rr < cn) {
            float v = fmaxf(acc[mi][ni][rg] + bias, 0.f);
            hout[(size_t)(be + rr) * HID + col] = f2b(v);
          }
        }
    }
  } else if (MODE == 2) {
    const float* bb = b2 + (size_t)e * HID;
    const float* bq = bp + (size_t)e * HID;
#pragma unroll
    for (int ni = 0; ni < 4; ++ni) {
      int col = ccol0 + ni * 16;
      float bias = bb[col] + bq[col];
#pragma unroll
      for (int mi = 0; mi < 4; ++mi)
#pragma unroll
        for (int rg = 0; rg < 4; ++rg) {
          int rr = crow + mi * 16 + rg;
          if (rr < cn) {
            float v = fmaxf(acc[mi][ni][rg] + bias, 0.f);
            oout[(size_t)(be + rr) * HID + col] = f2b(v);
          }
        }
    }
  } else {
    const float* bb = b3 + (size_t)e * DOUTN;
    float biasv[4];
#pragma unroll
    for (int ni = 0; ni < 4; ++ni) biasv[ni] = bb[ccol0 + ni * 16];
#pragma unroll
    for (int mi = 0; mi < 4; ++mi)
#pragma unroll
      for (int rg = 0; rg < 4; ++rg) {
        int rr = crow + mi * 16 + rg;
        if (rr < cn) {
          int tk = rt[be + rr];
          float wgt = rw[be + rr];
#pragma unroll
          for (int ni = 0; ni < 4; ++ni) {
            int col = ccol0 + ni * 16;
            atomicAdd(dout + (size_t)tk * DOUTN + col,
                      (acc[mi][ni][rg] + biasv[ni]) * wgt);
          }
        }
      }
  }
}

// ---------------- launch ----------------

extern "C" void kernel_launch(void* const* d_in, const int* in_sizes, int n_in,
                              void* d_out, int out_size, void* d_ws,
                              size_t ws_size, hipStream_t stream) {
  const float* x = (const float*)d_in[0];
  const float* w1 = (const float*)d_in[1];
  const float* b1 = (const float*)d_in[2];
  const float* w2 = (const float*)d_in[3];
  const float* b2 = (const float*)d_in[4];
  const float* w3 = (const float*)d_in[5];
  const float* b3 = (const float*)d_in[6];
  const float* wp = (const float*)d_in[7];
  const float* bp = (const float*)d_in[8];
  const float* gw1 = (const float*)d_in[9];
  const float* gb1 = (const float*)d_in[10];
  const float* gw2 = (const float*)d_in[11];
  const float* gb2 = (const float*)d_in[12];
  float* outp = (float*)d_out;
  char* ws = (char*)d_ws;

  // workspace layout (~336.3 MiB)
  const size_t o_w1t = 0;
  const size_t o_wpt = o_w1t + (size_t)NEXP * HID * DIN * 2;
  const size_t o_w2t = o_wpt + (size_t)NEXP * HID * DIN * 2;
  const size_t o_w3t = o_w2t + (size_t)NEXP * HID * HID * 2;
  const size_t o_xb  = o_w3t + (size_t)NEXP * DOUTN * HID * 2;
  const size_t o_hg  = o_xb + (size_t)TOK * DIN * 2;
  const size_t o_h   = o_hg + (size_t)TOK * GHID * 4;
  const size_t o_ob  = o_h + (size_t)2 * TOK * HID * 2;
  const size_t o_gidx = o_ob + (size_t)2 * TOK * HID * 2;
  const size_t o_gw  = o_gidx + (size_t)2 * TOK * 4;
  const size_t o_cnt = o_gw + (size_t)2 * TOK * 4;
  const size_t o_base = o_cnt + 128;
  const size_t o_cur = o_base + 128;
  const size_t o_rt  = o_cur + 128;
  const size_t o_rw  = o_rt + (size_t)2 * TOK * 4;

  unsigned short* w1t = (unsigned short*)(ws + o_w1t);
  unsigned short* wpt = (unsigned short*)(ws + o_wpt);
  unsigned short* w2t = (unsigned short*)(ws + o_w2t);
  unsigned short* w3t = (unsigned short*)(ws + o_w3t);
  unsigned short* xb = (unsigned short*)(ws + o_xb);
  float* hg = (float*)(ws + o_hg);
  unsigned short* hbuf = (unsigned short*)(ws + o_h);
  unsigned short* obuf = (unsigned short*)(ws + o_ob);
  int* gidx = (int*)(ws + o_gidx);
  float* gwt = (float*)(ws + o_gw);
  int* cnt = (int*)(ws + o_cnt);
  int* basep = (int*)(ws + o_base);
  int* cur = (int*)(ws + o_cur);
  int* rtl = (int*)(ws + o_rt);
  float* rwl = (float*)(ws + o_rw);

  hipMemsetAsync(d_out, 0, (size_t)out_size * 4, stream);
  hipMemsetAsync(ws + o_cnt, 0, 32, stream);

  cvt_x_kernel<<<dim3(TOK * DIN / 4 / 256), 256, 0, stream>>>(x, xb, TOK * DIN / 4);
  cvt_transpose_kernel<<<dim3(HID / 32, DIN / 32, NEXP), dim3(32, 8), 0, stream>>>(w1, w1t, DIN, HID);
  cvt_transpose_kernel<<<dim3(HID / 32, DIN / 32, NEXP), dim3(32, 8), 0, stream>>>(wp, wpt, DIN, HID);
  cvt_transpose_kernel<<<dim3(HID / 32, HID / 32, NEXP), dim3(32, 8), 0, stream>>>(w2, w2t, HID, HID);
  cvt_transpose_kernel<<<dim3(DOUTN / 32, HID / 32, NEXP), dim3(32, 8), 0, stream>>>(w3, w3t, HID, DOUTN);

  gating_sgemm<<<dim3(GHID / 128, TOK / 128), 256, 0, stream>>>(x, gw1, gb1, hg);
  gating2_topk<<<dim3(TOK / 4), 256, 0, stream>>>(hg, gw2, gb2, gidx, gwt);
  route_count<<<dim3(TOK / 256), 256, 0, stream>>>(gidx, cnt);
  route_scan<<<1, 64, 0, stream>>>(cnt, basep, cur);
  route_scatter<<<dim3(TOK / 256), 256, 0, stream>>>(gidx, gwt, cur, rtl, rwl);

  moe_gemm<1><<<dim3(HID / 128, 135), 256, 0, stream>>>(
      xb, hbuf, obuf, w1t, wpt, w2t, w3t, b1, b2, bp, b3, rtl, rwl, cnt, basep,
      hbuf, obuf, outp);
  moe_gemm<2><<<dim3(HID / 128, 135), 256, 0, stream>>>(
      xb, hbuf, obuf, w1t, wpt, w2t, w3t, b1, b2, bp, b3, rtl, rwl, cnt, basep,
      hbuf, obuf, outp);
  moe_gemm<3><<<dim3(DOUTN / 128, 135), 256, 0, stream>>>(
      xb, hbuf, obuf, w1t, wpt, w2t, w3t, b1, b2, bp, b3, rtl, rwl, cnt, basep,
      hbuf, obuf, outp);
}

// Round 2
// 1123.411 us; speedup vs baseline: 1.0945x; 1.0945x over previous
//
#include <hip/hip_runtime.h>
#include <hip/hip_bf16.h>
#include <cstdint>
#include <cstddef>

#define TOK  8192
#define DIN  1024
#define HID  2048
#define DOUTN 1024
#define NEXP 8
#define GHID 1024

typedef __attribute__((ext_vector_type(8))) short bf16x8;
typedef __attribute__((ext_vector_type(4))) float floatx4;

__device__ __forceinline__ unsigned short f2b(float f) {
  unsigned int u = __float_as_uint(f);
  u += 0x7fffu + ((u >> 16) & 1u);
  return (unsigned short)(u >> 16);
}

__device__ __forceinline__ float b2f(unsigned short b) {
  return __uint_as_float(((unsigned int)b) << 16);
}

__device__ __forceinline__ void async_cp16(const unsigned short* g, char* lds) {
  __builtin_amdgcn_global_load_lds(
      (const __attribute__((address_space(1))) unsigned int*)g,
      (__attribute__((address_space(3))) unsigned int*)lds, 16, 0, 0);
}

// ---------------- conversions ----------------

// x fp32 -> xb (bf16 hi) and xcat [TOK][3072] = [hi | hi | lo]
__global__ void cvt_x_kernel(const float* __restrict__ src,
                             unsigned short* __restrict__ xb,
                             unsigned short* __restrict__ xcat, int n4) {
  int i = blockIdx.x * blockDim.x + threadIdx.x;
  if (i >= n4) return;
  float4 v = ((const float4*)src)[i];
  ushort4 hi, lo;
  hi.x = f2b(v.x); lo.x = f2b(v.x - b2f(hi.x));
  hi.y = f2b(v.y); lo.y = f2b(v.y - b2f(hi.y));
  hi.z = f2b(v.z); lo.z = f2b(v.z - b2f(hi.z));
  hi.w = f2b(v.w); lo.w = f2b(v.w - b2f(hi.w));
  ((ushort4*)xb)[i] = hi;
  int t = i >> 8;        // DIN/4 = 256 float4 per row
  int kk = i & 255;
  ushort4* rowc = (ushort4*)(xcat + (size_t)t * 3072);
  rowc[kk] = hi;
  rowc[256 + kk] = hi;
  rowc[512 + kk] = lo;
}

// src [E][K][N] fp32 -> dst [E][N][K] bf16
__global__ void cvt_transpose_kernel(const float* __restrict__ src,
                                     unsigned short* __restrict__ dst,
                                     int K, int N) {
  __shared__ float tile[32][33];
  long e = blockIdx.z;
  src += e * (long)K * N;
  dst += e * (long)K * N;
  int n0 = blockIdx.x * 32, k0 = blockIdx.y * 32;
  int x = threadIdx.x, y = threadIdx.y;
#pragma unroll
  for (int i = 0; i < 4; i++)
    tile[y + 8 * i][x] = src[(long)(k0 + y + 8 * i) * N + n0 + x];
  __syncthreads();
#pragma unroll
  for (int i = 0; i < 4; i++)
    dst[(long)(n0 + y + 8 * i) * K + k0 + x] = f2b(tile[x][y + 8 * i]);
}

// gw1 [DIN][GHID] fp32 -> gw1t3 [GHID][3072] bf16 = [W_hi^T | W_lo^T | W_hi^T]
__global__ void cvt_gw1_kernel(const float* __restrict__ src,
                               unsigned short* __restrict__ dst) {
  __shared__ float tile[32][33];
  int n0 = blockIdx.x * 32, k0 = blockIdx.y * 32;
  int x = threadIdx.x, y = threadIdx.y;
#pragma unroll
  for (int i = 0; i < 4; i++)
    tile[y + 8 * i][x] = src[(long)(k0 + y + 8 * i) * GHID + n0 + x];
  __syncthreads();
#pragma unroll
  for (int i = 0; i < 4; i++) {
    float v = tile[x][y + 8 * i];
    unsigned short hi = f2b(v);
    unsigned short lo = f2b(v - b2f(hi));
    size_t r = (size_t)(n0 + y + 8 * i) * 3072 + k0 + x;
    dst[r] = hi;
    dst[r + 1024] = lo;
    dst[r + 2048] = hi;
  }
}

// ---------------- MFMA K-loop body (shared) ----------------

#define KLOOP(pa0, pa1, pb0, pb1, NKT)                                        \
  for (int kt = 0; kt < (NKT); ++kt) {                                        \
    __syncthreads();                                                          \
    async_cp16((pa0) + kt * 32, ldsA0);                                       \
    async_cp16((pa1) + kt * 32, ldsA0 + 4096);                                \
    async_cp16((pb0) + kt * 32, ldsB0);                                       \
    async_cp16((pb1) + kt * 32, ldsB0 + 4096);                                \
    __syncthreads();                                                          \
    bf16x8 af[4], bfr[4];                                                     \
    _Pragma("unroll") for (int i = 0; i < 4; i++) {                           \
      af[i] = *(const bf16x8*)(AsB + i * 1024);                               \
      bfr[i] = *(const bf16x8*)(BsB + i * 1024);                              \
    }                                                                         \
    _Pragma("unroll") for (int mi = 0; mi < 4; mi++)                          \
      _Pragma("unroll") for (int ni = 0; ni < 4; ni++)                        \
        acc[mi][ni] = __builtin_amdgcn_mfma_f32_16x16x32_bf16(                \
            af[mi], bfr[ni], acc[mi][ni], 0, 0, 0);                           \
  }

#define TILE_SETUP()                                                          \
  int tid = threadIdx.x;                                                      \
  int sr = tid >> 2;                                                          \
  int lchunk = (tid & 3) ^ ((sr >> 1) & 3);                                   \
  int koffA = lchunk * 8;                                                     \
  char* ldsA0 = (char*)As + (tid & 192) * 16;                                 \
  char* ldsB0 = (char*)Bs + (tid & 192) * 16;                                 \
  int lane = tid & 63, wv = tid >> 6;                                         \
  int wm = (wv >> 1) << 6, wn = (wv & 1) << 6;                                \
  int q = lane >> 4, l15 = lane & 15;                                         \
  int abase = l15 * 64 + ((q ^ ((l15 >> 1) & 3)) << 4);                       \
  const char* AsB = (const char*)As + wm * 64 + abase;                        \
  const char* BsB = (const char*)Bs + wn * 64 + abase;                        \
  floatx4 acc[4][4] = {};

// ---------------- gating layer-1: split-bf16 MFMA GEMM ----------------
// H = relu(xcat @ gw1t3^T + gb1), M=8192, N=1024, K=3072, fp32 out

__global__ __launch_bounds__(256, 2) void gating_mfma(
    const unsigned short* __restrict__ xcat,
    const unsigned short* __restrict__ gw1t3,
    const float* __restrict__ gb1, float* __restrict__ H) {
  __shared__ __align__(16) unsigned short As[128 * 32];
  __shared__ __align__(16) unsigned short Bs[128 * 32];
  TILE_SETUP();
  int row0 = blockIdx.y << 7, tn = blockIdx.x << 7;

  const unsigned short* a0p = xcat + (size_t)(row0 + sr) * 3072 + koffA;
  const unsigned short* a1p = xcat + (size_t)(row0 + 64 + sr) * 3072 + koffA;
  const unsigned short* b0p = gw1t3 + (size_t)(tn + sr) * 3072 + koffA;
  const unsigned short* b1p = gw1t3 + (size_t)(tn + 64 + sr) * 3072 + koffA;

  KLOOP(a0p, a1p, b0p, b1p, 3072 / 32);

  int crow = row0 + wm + q * 4;
  int ccol0 = tn + wn + l15;
#pragma unroll
  for (int ni = 0; ni < 4; ++ni) {
    int col = ccol0 + ni * 16;
    float bias = gb1[col];
#pragma unroll
    for (int mi = 0; mi < 4; ++mi)
#pragma unroll
      for (int rg = 0; rg < 4; ++rg) {
        int rr = crow + mi * 16 + rg;
        H[(size_t)rr * GHID + col] = fmaxf(acc[mi][ni][rg] + bias, 0.f);
      }
  }
}

// ---------------- gating: logits + top-2 + softmax ----------------

__global__ void gating2_topk(const float* __restrict__ H,
                             const float* __restrict__ gw2,
                             const float* __restrict__ gb2,
                             int* __restrict__ gidx, float* __restrict__ gwt) {
  int wv = threadIdx.x >> 6, lane = threadIdx.x & 63;
  int t = blockIdx.x * 4 + wv;
  const float* hrow = H + (size_t)t * GHID;
  float acc[8] = {};
  for (int k = lane; k < GHID; k += 64) {
    float v = hrow[k];
    float4 g0 = *(const float4*)(gw2 + (size_t)k * 8);
    float4 g1 = *(const float4*)(gw2 + (size_t)k * 8 + 4);
    acc[0] += v * g0.x; acc[1] += v * g0.y; acc[2] += v * g0.z; acc[3] += v * g0.w;
    acc[4] += v * g1.x; acc[5] += v * g1.y; acc[6] += v * g1.z; acc[7] += v * g1.w;
  }
#pragma unroll
  for (int off = 32; off > 0; off >>= 1)
#pragma unroll
    for (int e = 0; e < 8; e++) acc[e] += __shfl_xor(acc[e], off);

  if (lane == 0) {
    float l[8];
#pragma unroll
    for (int e = 0; e < 8; e++) l[e] = acc[e] + gb2[e];
    int b0 = 0; float v0 = l[0];
#pragma unroll
    for (int e = 1; e < 8; e++) if (l[e] > v0) { v0 = l[e]; b0 = e; }
    int b1 = -1; float v1 = -3.4e38f;
#pragma unroll
    for (int e = 0; e < 8; e++)
      if (e != b0 && l[e] > v1) { v1 = l[e]; b1 = e; }
    float ex = expf(v1 - v0);
    float inv = 1.f / (1.f + ex);
    gidx[2 * t] = b0; gidx[2 * t + 1] = b1;
    gwt[2 * t] = inv; gwt[2 * t + 1] = ex * inv;
  }
}

// ---------------- routing: count / scan / scatter ----------------

__global__ void route_count(const int* __restrict__ gidx, int* cnt) {
  int t = blockIdx.x * blockDim.x + threadIdx.x;
  int lane = threadIdx.x & 63;
  int e0 = gidx[2 * t], e1 = gidx[2 * t + 1];
#pragma unroll 1
  for (int e = 0; e < NEXP; e++) {
    unsigned long long m0 = __ballot(e0 == e);
    if (m0 && lane == __ffsll(m0) - 1) atomicAdd(&cnt[e], (int)__popcll(m0));
    unsigned long long m1 = __ballot(e1 == e);
    if (m1 && lane == __ffsll(m1) - 1) atomicAdd(&cnt[e], (int)__popcll(m1));
  }
}

__global__ void route_scan(const int* __restrict__ cnt, int* base_, int* cur) {
  if (threadIdx.x == 0) {
    int s = 0;
    for (int e = 0; e < NEXP; e++) { base_[e] = s; cur[e] = s; s += cnt[e]; }
  }
}

__global__ void route_scatter(const int* __restrict__ gidx,
                              const float* __restrict__ gwt, int* cur,
                              int* __restrict__ rt, float* __restrict__ rw) {
  int t = blockIdx.x * blockDim.x + threadIdx.x;
  int lane = threadIdx.x & 63;
  int e0 = gidx[2 * t], e1 = gidx[2 * t + 1];
  float w0 = gwt[2 * t], w1 = gwt[2 * t + 1];
#pragma unroll 1
  for (int e = 0; e < NEXP; e++) {
#pragma unroll 1
    for (int s = 0; s < 2; s++) {
      int mye = s ? e1 : e0;
      unsigned long long m = __ballot(mye == e);
      if (m) {
        int leader = __ffsll(m) - 1;
        int bb = 0;
        if (lane == leader) bb = atomicAdd(&cur[e], (int)__popcll(m));
        bb = __shfl(bb, leader);
        if (mye == e) {
          int pos = bb + (int)__popcll(m & ((1ull << lane) - 1ull));
          rt[pos] = t;
          rw[pos] = s ? w1 : w0;
        }
      }
    }
  }
}

// ---------------- expert GEMMs (bf16 MFMA, 128x128x32) ----------------
// MODE 1: h   = relu(Xg @ w1 + b1)                   K=1024
// MODE 2: out = relu(h @ w2 + Xg @ wp + b2 + bp)     K=2048+1024 (two phases)
// MODE 3: d_out += gatew * (out @ w3 + b3)           K=2048 (atomic scatter)

template <int MODE>
__global__ __launch_bounds__(256, 2) void moe_gemm(
    const unsigned short* __restrict__ xb, const unsigned short* __restrict__ hbuf,
    const unsigned short* __restrict__ obuf, const unsigned short* __restrict__ w1t,
    const unsigned short* __restrict__ wpt, const unsigned short* __restrict__ w2t,
    const unsigned short* __restrict__ w3t, const float* __restrict__ b1,
    const float* __restrict__ b2, const float* __restrict__ bp,
    const float* __restrict__ b3, const int* __restrict__ rt,
    const float* __restrict__ rw, const int* __restrict__ cnt,
    const int* __restrict__ base, unsigned short* __restrict__ hout,
    unsigned short* __restrict__ oout, float* __restrict__ dout) {
  __shared__ __align__(16) unsigned short As[128 * 32];
  __shared__ __align__(16) unsigned short Bs[128 * 32];

  // map blockIdx.y -> (expert, local row tile)
  int lt = blockIdx.y;
  int e = 0, cn = 0, ok = 0;
  for (e = 0; e < NEXP; ++e) {
    int c = cnt[e];
    int nt = (c + 127) >> 7;
    if (lt < nt) { cn = c; ok = 1; break; }
    lt -= nt;
  }
  if (!ok) return;
  int be = base[e];
  int row0 = lt << 7;
  int tn = blockIdx.x << 7;

  TILE_SETUP();

  int rl0 = row0 + sr, rl1 = row0 + 64 + sr;
  int cl0 = min(rl0, cn - 1), cl1 = min(rl1, cn - 1);

  if (MODE == 1) {
    const unsigned short* a0p = xb + (size_t)rt[be + cl0] * DIN + koffA;
    const unsigned short* a1p = xb + (size_t)rt[be + cl1] * DIN + koffA;
    const unsigned short* bw0 = w1t + ((size_t)e * HID + tn + sr) * DIN + koffA;
    const unsigned short* bw1 = w1t + ((size_t)e * HID + tn + 64 + sr) * DIN + koffA;
    KLOOP(a0p, a1p, bw0, bw1, DIN / 32);
  } else if (MODE == 2) {
    const unsigned short* a0p = hbuf + (size_t)(be + cl0) * HID + koffA;
    const unsigned short* a1p = hbuf + (size_t)(be + cl1) * HID + koffA;
    const unsigned short* bw0 = w2t + (size_t)e * HID * HID + (size_t)(tn + sr) * HID + koffA;
    const unsigned short* bw1 = w2t + (size_t)e * HID * HID + (size_t)(tn + 64 + sr) * HID + koffA;
    KLOOP(a0p, a1p, bw0, bw1, HID / 32);
    const unsigned short* a0q = xb + (size_t)rt[be + cl0] * DIN + koffA;
    const unsigned short* a1q = xb + (size_t)rt[be + cl1] * DIN + koffA;
    const unsigned short* bq0 = wpt + (size_t)e * HID * DIN + (size_t)(tn + sr) * DIN + koffA;
    const unsigned short* bq1 = wpt + (size_t)e * HID * DIN + (size_t)(tn + 64 + sr) * DIN + koffA;
    KLOOP(a0q, a1q, bq0, bq1, DIN / 32);
  } else {
    const unsigned short* a0p = obuf + (size_t)(be + cl0) * HID + koffA;
    const unsigned short* a1p = obuf + (size_t)(be + cl1) * HID + koffA;
    const unsigned short* bw0 = w3t + (size_t)e * DOUTN * HID + (size_t)(tn + sr) * HID + koffA;
    const unsigned short* bw1 = w3t + (size_t)e * DOUTN * HID + (size_t)(tn + 64 + sr) * HID + koffA;
    KLOOP(a0p, a1p, bw0, bw1, HID / 32);
  }

  // ---- epilogue (C/D: col=lane&15, row=quad*4+reg) ----
  int crow = row0 + wm + q * 4;
  int ccol0 = tn + wn + l15;
  if (MODE == 1) {
    const float* bb = b1 + (size_t)e * HID;
#pragma unroll
    for (int ni = 0; ni < 4; ++ni) {
      int col = ccol0 + ni * 16;
      float bias = bb[col];
#pragma unroll
      for (int mi = 0; mi < 4; ++mi)
#pragma unroll
        for (int rg = 0; rg < 4; ++rg) {
          int rr = crow + mi * 16 + rg;
          if (rr < cn) {
            float v = fmaxf(acc[mi][ni][rg] + bias, 0.f);
            hout[(size_t)(be + rr) * HID + col] = f2b(v);
          }
        }
    }
  } else if (MODE == 2) {
    const float* bb = b2 + (size_t)e * HID;
    const float* bq = bp + (size_t)e * HID;
#pragma unroll
    for (int ni = 0; ni < 4; ++ni) {
      int col = ccol0 + ni * 16;
      float bias = bb[col] + bq[col];
#pragma unroll
      for (int mi = 0; mi < 4; ++mi)
#pragma unroll
        for (int rg = 0; rg < 4; ++rg) {
          int rr = crow + mi * 16 + rg;
          if (rr < cn) {
            float v = fmaxf(acc[mi][ni][rg] + bias, 0.f);
            oout[(size_t)(be + rr) * HID + col] = f2b(v);
          }
        }
    }
  } else {
    const float* bb = b3 + (size_t)e * DOUTN;
    float biasv[4];
#pragma unroll
    for (int ni = 0; ni < 4; ++ni) biasv[ni] = bb[ccol0 + ni * 16];
#pragma unroll
    for (int mi = 0; mi < 4; ++mi)
#pragma unroll
      for (int rg = 0; rg < 4; ++rg) {
        int rr = crow + mi * 16 + rg;
        if (rr < cn) {
          int tk = rt[be + rr];
          float wgt = rw[be + rr];
#pragma unroll
          for (int ni = 0; ni < 4; ++ni) {
            int col = ccol0 + ni * 16;
            atomicAdd(dout + (size_t)tk * DOUTN + col,
                      (acc[mi][ni][rg] + biasv[ni]) * wgt);
          }
        }
      }
  }
}

// ---------------- launch ----------------

extern "C" void kernel_launch(void* const* d_in, const int* in_sizes, int n_in,
                              void* d_out, int out_size, void* d_ws,
                              size_t ws_size, hipStream_t stream) {
  const float* x = (const float*)d_in[0];
  const float* w1 = (const float*)d_in[1];
  const float* b1 = (const float*)d_in[2];
  const float* w2 = (const float*)d_in[3];
  const float* b2 = (const float*)d_in[4];
  const float* w3 = (const float*)d_in[5];
  const float* b3 = (const float*)d_in[6];
  const float* wp = (const float*)d_in[7];
  const float* bp = (const float*)d_in[8];
  const float* gw1 = (const float*)d_in[9];
  const float* gb1 = (const float*)d_in[10];
  const float* gw2 = (const float*)d_in[11];
  const float* gb2 = (const float*)d_in[12];
  float* outp = (float*)d_out;
  char* ws = (char*)d_ws;

  // workspace layout (~336 MiB, xcat/gw1t3 alias later-phase buffers)
  const size_t o_w1t = 0;
  const size_t o_wpt = o_w1t + (size_t)NEXP * HID * DIN * 2;
  const size_t o_w2t = o_wpt + (size_t)NEXP * HID * DIN * 2;
  const size_t o_w3t = o_w2t + (size_t)NEXP * HID * HID * 2;
  const size_t o_xb  = o_w3t + (size_t)NEXP * DOUTN * HID * 2;
  const size_t o_hg  = o_xb + (size_t)TOK * DIN * 2;
  const size_t o_h   = o_hg + (size_t)TOK * GHID * 4;
  const size_t o_ob  = o_h + (size_t)2 * TOK * HID * 2;
  const size_t o_gidx = o_ob + (size_t)2 * TOK * HID * 2;
  const size_t o_gw  = o_gidx + (size_t)2 * TOK * 4;
  const size_t o_cnt = o_gw + (size_t)2 * TOK * 4;
  const size_t o_base = o_cnt + 128;
  const size_t o_cur = o_base + 128;
  const size_t o_rt  = o_cur + 128;
  const size_t o_rw  = o_rt + (size_t)2 * TOK * 4;
  // aliases (sequential-stream safe):
  const size_t o_xcat = o_ob;   // xcat [TOK][3072] bf16 (50 MB) in obuf region (67 MB)
  const size_t o_gw1t3 = o_h;   // gw1t3 [GHID][3072] bf16 (6.3 MB) in hbuf region

  unsigned short* w1t = (unsigned short*)(ws + o_w1t);
  unsigned short* wpt = (unsigned short*)(ws + o_wpt);
  unsigned short* w2t = (unsigned short*)(ws + o_w2t);
  unsigned short* w3t = (unsigned short*)(ws + o_w3t);
  unsigned short* xb = (unsigned short*)(ws + o_xb);
  float* hg = (float*)(ws + o_hg);
  unsigned short* hbuf = (unsigned short*)(ws + o_h);
  unsigned short* obuf = (unsigned short*)(ws + o_ob);
  unsigned short* xcat = (unsigned short*)(ws + o_xcat);
  unsigned short* gw1t3 = (unsigned short*)(ws + o_gw1t3);
  int* gidx = (int*)(ws + o_gidx);
  float* gwt = (float*)(ws + o_gw);
  int* cnt = (int*)(ws + o_cnt);
  int* basep = (int*)(ws + o_base);
  int* cur = (int*)(ws + o_cur);
  int* rtl = (int*)(ws + o_rt);
  float* rwl = (float*)(ws + o_rw);

  hipMemsetAsync(d_out, 0, (size_t)out_size * 4, stream);
  hipMemsetAsync(ws + o_cnt, 0, 32, stream);

  cvt_x_kernel<<<dim3(TOK * DIN / 4 / 256), 256, 0, stream>>>(x, xb, xcat, TOK * DIN / 4);
  cvt_gw1_kernel<<<dim3(GHID / 32, DIN / 32), dim3(32, 8), 0, stream>>>(gw1, gw1t3);
  cvt_transpose_kernel<<<dim3(HID / 32, DIN / 32, NEXP), dim3(32, 8), 0, stream>>>(w1, w1t, DIN, HID);
  cvt_transpose_kernel<<<dim3(HID / 32, DIN / 32, NEXP), dim3(32, 8), 0, stream>>>(wp, wpt, DIN, HID);
  cvt_transpose_kernel<<<dim3(HID / 32, HID / 32, NEXP), dim3(32, 8), 0, stream>>>(w2, w2t, HID, HID);
  cvt_transpose_kernel<<<dim3(DOUTN / 32, HID / 32, NEXP), dim3(32, 8), 0, stream>>>(w3, w3t, HID, DOUTN);

  gating_mfma<<<dim3(GHID / 128, TOK / 128), 256, 0, stream>>>(xcat, gw1t3, gb1, hg);
  gating2_topk<<<dim3(TOK / 4), 256, 0, stream>>>(hg, gw2, gb2, gidx, gwt);
  route_count<<<dim3(TOK / 256), 256, 0, stream>>>(gidx, cnt);
  route_scan<<<1, 64, 0, stream>>>(cnt, basep, cur);
  route_scatter<<<dim3(TOK / 256), 256, 0, stream>>>(gidx, gwt, cur, rtl, rwl);

  moe_gemm<1><<<dim3(HID / 128, 135), 256, 0, stream>>>(
      xb, hbuf, obuf, w1t, wpt, w2t, w3t, b1, b2, bp, b3, rtl, rwl, cnt, basep,
      hbuf, obuf, outp);
  moe_gemm<2><<<dim3(HID / 128, 135), 256, 0, stream>>>(
      xb, hbuf, obuf, w1t, wpt, w2t, w3t, b1, b2, bp, b3, rtl, rwl, cnt, basep,
      hbuf, obuf, outp);
  moe_gemm<3><<<dim3(DOUTN / 128, 135), 256, 0, stream>>>(
      xb, hbuf, obuf, w1t, wpt, w2t, w3t, b1, b2, bp, b3, rtl, rwl, cnt, basep,
      hbuf, obuf, outp);
}

// Round 3
// 1118.294 us; speedup vs baseline: 1.0995x; 1.0046x over previous
//
#include <hip/hip_runtime.h>
#include <hip/hip_bf16.h>
#include <cstdint>
#include <cstddef>

#define TOK  8192
#define DIN  1024
#define HID  2048
#define DOUTN 1024
#define NEXP 8
#define GHID 1024

typedef __attribute__((ext_vector_type(8))) short bf16x8;
typedef __attribute__((ext_vector_type(4))) float floatx4;
typedef __attribute__((ext_vector_type(8))) unsigned short ushort8v;

__device__ __forceinline__ unsigned short f2b(float f) {
  unsigned int u = __float_as_uint(f);
  u += 0x7fffu + ((u >> 16) & 1u);
  return (unsigned short)(u >> 16);
}

__device__ __forceinline__ float b2f(unsigned short b) {
  return __uint_as_float(((unsigned int)b) << 16);
}

__device__ __forceinline__ void async_cp16(const unsigned short* g, char* lds) {
  __builtin_amdgcn_global_load_lds(
      (const __attribute__((address_space(1))) unsigned int*)g,
      (__attribute__((address_space(3))) unsigned int*)lds, 16, 0, 0);
}

// ---------------- conversions ----------------

// x fp32 -> xb (bf16 hi) and xcat [TOK][3072] = [hi | hi | lo] (gating A operand)
__global__ void cvt_x_kernel(const float* __restrict__ src,
                             unsigned short* __restrict__ xb,
                             unsigned short* __restrict__ xcat, int n4) {
  int i = blockIdx.x * blockDim.x + threadIdx.x;
  if (i >= n4) return;
  float4 v = ((const float4*)src)[i];
  ushort4 hi, lo;
  hi.x = f2b(v.x); lo.x = f2b(v.x - b2f(hi.x));
  hi.y = f2b(v.y); lo.y = f2b(v.y - b2f(hi.y));
  hi.z = f2b(v.z); lo.z = f2b(v.z - b2f(hi.z));
  hi.w = f2b(v.w); lo.w = f2b(v.w - b2f(hi.w));
  ((ushort4*)xb)[i] = hi;
  int t = i >> 8;        // DIN/4 = 256 float4 per row
  int kk = i & 255;
  ushort4* rowc = (ushort4*)(xcat + (size_t)t * 3072);
  rowc[kk] = hi;
  rowc[256 + kk] = hi;
  rowc[512 + kk] = lo;
}

// src [E][K][N] fp32 -> dst [E][N][ldDst] bf16 (64x64 tiles, vectorized)
__global__ void cvt_transpose_v2(const float* __restrict__ src,
                                 unsigned short* __restrict__ dst, int N,
                                 long sEstride, long dEstride, int ldDst) {
  __shared__ __align__(16) unsigned short t[64][72];
  long e = blockIdx.z;
  src += e * sEstride;
  dst += e * dEstride;
  int n0 = blockIdx.x * 64, k0 = blockIdx.y * 64;
  int tid = threadIdx.x;
  int kr = tid >> 2, qc = tid & 3;
  const float* s = src + (long)(k0 + kr) * N + n0 + qc * 16;
#pragma unroll
  for (int i = 0; i < 4; i++) {
    float4 v = *(const float4*)(s + i * 4);
    int nn = qc * 16 + i * 4;
    t[nn + 0][kr] = f2b(v.x);
    t[nn + 1][kr] = f2b(v.y);
    t[nn + 2][kr] = f2b(v.z);
    t[nn + 3][kr] = f2b(v.w);
  }
  __syncthreads();
  int c = tid & 7;     // 16B chunk along k
  int nr = tid >> 3;   // 0..31
#pragma unroll
  for (int p = 0; p < 2; p++) {
    int n = nr + 32 * p;
    ushort8v v = *(const ushort8v*)&t[n][c * 8];
    *(ushort8v*)(dst + (long)(n0 + n) * ldDst + k0 + c * 8) = v;
  }
}

// gw1 [DIN][GHID] fp32 -> gw1t3 [GHID][3072] bf16 = [W_hi^T | W_lo^T | W_hi^T]
__global__ void cvt_gw1_kernel(const float* __restrict__ src,
                               unsigned short* __restrict__ dst) {
  __shared__ float tile[32][33];
  int n0 = blockIdx.x * 32, k0 = blockIdx.y * 32;
  int x = threadIdx.x, y = threadIdx.y;
#pragma unroll
  for (int i = 0; i < 4; i++)
    tile[y + 8 * i][x] = src[(long)(k0 + y + 8 * i) * GHID + n0 + x];
  __syncthreads();
#pragma unroll
  for (int i = 0; i < 4; i++) {
    float v = tile[x][y + 8 * i];
    unsigned short hi = f2b(v);
    unsigned short lo = f2b(v - b2f(hi));
    size_t r = (size_t)(n0 + y + 8 * i) * 3072 + k0 + x;
    dst[r] = hi;
    dst[r + 1024] = lo;
    dst[r + 2048] = hi;
  }
}

// ---------------- MFMA K-loop body (shared) ----------------

#define KLOOP(pa0, pa1, pb0, pb1, NKT)                                        \
  for (int kt = 0; kt < (NKT); ++kt) {                                        \
    __syncthreads();                                                          \
    async_cp16((pa0) + kt * 32, ldsA0);                                       \
    async_cp16((pa1) + kt * 32, ldsA0 + 4096);                                \
    async_cp16((pb0) + kt * 32, ldsB0);                                       \
    async_cp16((pb1) + kt * 32, ldsB0 + 4096);                                \
    __syncthreads();                                                          \
    bf16x8 af[4], bfr[4];                                                     \
    _Pragma("unroll") for (int i = 0; i < 4; i++) {                           \
      af[i] = *(const bf16x8*)(AsB + i * 1024);                               \
      bfr[i] = *(const bf16x8*)(BsB + i * 1024);                              \
    }                                                                         \
    _Pragma("unroll") for (int mi = 0; mi < 4; mi++)                          \
      _Pragma("unroll") for (int ni = 0; ni < 4; ni++)                        \
        acc[mi][ni] = __builtin_amdgcn_mfma_f32_16x16x32_bf16(                \
            af[mi], bfr[ni], acc[mi][ni], 0, 0, 0);                           \
  }

#define TILE_SETUP()                                                          \
  int tid = threadIdx.x;                                                      \
  int sr = tid >> 2;                                                          \
  int lchunk = (tid & 3) ^ ((sr >> 1) & 3);                                   \
  int koffA = lchunk * 8;                                                     \
  char* ldsA0 = (char*)As + (tid & 192) * 16;                                 \
  char* ldsB0 = (char*)Bs + (tid & 192) * 16;                                 \
  int lane = tid & 63, wv = tid >> 6;                                         \
  int wm = (wv >> 1) << 6, wn = (wv & 1) << 6;                                \
  int q = lane >> 4, l15 = lane & 15;                                         \
  int abase = l15 * 64 + ((q ^ ((l15 >> 1) & 3)) << 4);                       \
  const char* AsB = (const char*)As + wm * 64 + abase;                        \
  const char* BsB = (const char*)Bs + wn * 64 + abase;                        \
  floatx4 acc[4][4] = {};

// ---------------- gating layer-1: split-bf16 MFMA GEMM ----------------

__global__ __launch_bounds__(256, 4) void gating_mfma(
    const unsigned short* __restrict__ xcat,
    const unsigned short* __restrict__ gw1t3,
    const float* __restrict__ gb1, float* __restrict__ H) {
  __shared__ __align__(16) unsigned short As[128 * 32];
  __shared__ __align__(16) unsigned short Bs[128 * 32];
  TILE_SETUP();
  int row0 = blockIdx.y << 7, tn = blockIdx.x << 7;

  const unsigned short* a0p = xcat + (size_t)(row0 + sr) * 3072 + koffA;
  const unsigned short* a1p = xcat + (size_t)(row0 + 64 + sr) * 3072 + koffA;
  const unsigned short* b0p = gw1t3 + (size_t)(tn + sr) * 3072 + koffA;
  const unsigned short* b1p = gw1t3 + (size_t)(tn + 64 + sr) * 3072 + koffA;

  KLOOP(a0p, a1p, b0p, b1p, 3072 / 32);

  int crow = row0 + wm + q * 4;
  int ccol0 = tn + wn + l15;
#pragma unroll
  for (int ni = 0; ni < 4; ++ni) {
    int col = ccol0 + ni * 16;
    float bias = gb1[col];
#pragma unroll
    for (int mi = 0; mi < 4; ++mi)
#pragma unroll
      for (int rg = 0; rg < 4; ++rg) {
        int rr = crow + mi * 16 + rg;
        H[(size_t)rr * GHID + col] = fmaxf(acc[mi][ni][rg] + bias, 0.f);
      }
  }
}

// ---------------- gating: logits + top-2 + softmax ----------------

__global__ void gating2_topk(const float* __restrict__ H,
                             const float* __restrict__ gw2,
                             const float* __restrict__ gb2,
                             int* __restrict__ gidx, float* __restrict__ gwt) {
  int wv = threadIdx.x >> 6, lane = threadIdx.x & 63;
  int t = blockIdx.x * 4 + wv;
  const float* hrow = H + (size_t)t * GHID;
  float acc[8] = {};
  for (int k = lane; k < GHID; k += 64) {
    float v = hrow[k];
    float4 g0 = *(const float4*)(gw2 + (size_t)k * 8);
    float4 g1 = *(const float4*)(gw2 + (size_t)k * 8 + 4);
    acc[0] += v * g0.x; acc[1] += v * g0.y; acc[2] += v * g0.z; acc[3] += v * g0.w;
    acc[4] += v * g1.x; acc[5] += v * g1.y; acc[6] += v * g1.z; acc[7] += v * g1.w;
  }
#pragma unroll
  for (int off = 32; off > 0; off >>= 1)
#pragma unroll
    for (int e = 0; e < 8; e++) acc[e] += __shfl_xor(acc[e], off);

  if (lane == 0) {
    float l[8];
#pragma unroll
    for (int e = 0; e < 8; e++) l[e] = acc[e] + gb2[e];
    int b0 = 0; float v0 = l[0];
#pragma unroll
    for (int e = 1; e < 8; e++) if (l[e] > v0) { v0 = l[e]; b0 = e; }
    int b1 = -1; float v1 = -3.4e38f;
#pragma unroll
    for (int e = 0; e < 8; e++)
      if (e != b0 && l[e] > v1) { v1 = l[e]; b1 = e; }
    float ex = expf(v1 - v0);
    float inv = 1.f / (1.f + ex);
    gidx[2 * t] = b0; gidx[2 * t + 1] = b1;
    gwt[2 * t] = inv; gwt[2 * t + 1] = ex * inv;
  }
}

// ---------------- routing: count / scan / scatter ----------------

__global__ void route_count(const int* __restrict__ gidx, int* cnt) {
  int t = blockIdx.x * blockDim.x + threadIdx.x;
  int lane = threadIdx.x & 63;
  int e0 = gidx[2 * t], e1 = gidx[2 * t + 1];
#pragma unroll 1
  for (int e = 0; e < NEXP; e++) {
    unsigned long long m0 = __ballot(e0 == e);
    if (m0 && lane == __ffsll(m0) - 1) atomicAdd(&cnt[e], (int)__popcll(m0));
    unsigned long long m1 = __ballot(e1 == e);
    if (m1 && lane == __ffsll(m1) - 1) atomicAdd(&cnt[e], (int)__popcll(m1));
  }
}

__global__ void route_scan(const int* __restrict__ cnt, int* base_, int* cur) {
  if (threadIdx.x == 0) {
    int s = 0;
    for (int e = 0; e < NEXP; e++) { base_[e] = s; cur[e] = s; s += cnt[e]; }
  }
}

__global__ void route_scatter(const int* __restrict__ gidx,
                              const float* __restrict__ gwt, int* cur,
                              int* __restrict__ rt, float* __restrict__ rw,
                              int* __restrict__ inv) {
  int t = blockIdx.x * blockDim.x + threadIdx.x;
  int lane = threadIdx.x & 63;
  int e0 = gidx[2 * t], e1 = gidx[2 * t + 1];
  float w0 = gwt[2 * t], w1 = gwt[2 * t + 1];
#pragma unroll 1
  for (int e = 0; e < NEXP; e++) {
#pragma unroll 1
    for (int s = 0; s < 2; s++) {
      int mye = s ? e1 : e0;
      unsigned long long m = __ballot(mye == e);
      if (m) {
        int leader = __ffsll(m) - 1;
        int bb = 0;
        if (lane == leader) bb = atomicAdd(&cur[e], (int)__popcll(m));
        bb = __shfl(bb, leader);
        if (mye == e) {
          int pos = bb + (int)__popcll(m & ((1ull << lane) - 1ull));
          rt[pos] = t;
          rw[pos] = s ? w1 : w0;
          inv[2 * t + s] = pos;
        }
      }
    }
  }
}

// gather x rows into hx[slot][2048..3071]
__global__ void xgather_kernel(const unsigned short* __restrict__ xb,
                               const int* __restrict__ rt,
                               unsigned short* __restrict__ hx) {
  int slot = blockIdx.x;
  int c = threadIdx.x;  // 128 threads x ushort8 = 1024 elems
  int t = rt[slot];
  ((ushort8v*)(hx + (size_t)slot * 3072 + 2048))[c] =
      ((const ushort8v*)(xb + (size_t)t * 1024))[c];
}

// out[t] = s3[inv[2t]] + s3[inv[2t+1]]
__global__ void combine_kernel(const float* __restrict__ s3,
                               const int* __restrict__ inv,
                               float* __restrict__ out) {
  int t = blockIdx.x;
  int c = threadIdx.x;  // 256 threads x float4 = 1024
  const float4* r0 = (const float4*)(s3 + (size_t)inv[2 * t] * DOUTN);
  const float4* r1 = (const float4*)(s3 + (size_t)inv[2 * t + 1] * DOUTN);
  float4 a = r0[c], b = r1[c];
  float4 o = {a.x + b.x, a.y + b.y, a.z + b.z, a.w + b.w};
  ((float4*)(out + (size_t)t * DOUTN))[c] = o;
}

// ---------------- expert GEMMs (bf16 MFMA, 128x128x32) ----------------
// MODE 1: hx[:,0:2048]  = relu(hx[:,2048:] @ w1 + b1)     K=1024
// MODE 2: obuf          = relu(hx @ [w2;wp] + b2 + bp)    K=3072
// MODE 3: s3            = (obuf @ w3 + b3) * gatew        K=2048 (plain store)

template <int MODE>
__global__ __launch_bounds__(256, 4) void moe_gemm(
    const unsigned short* __restrict__ hx, const unsigned short* __restrict__ obuf,
    const unsigned short* __restrict__ w1t, const unsigned short* __restrict__ w2p,
    const unsigned short* __restrict__ w3t, const float* __restrict__ b1,
    const float* __restrict__ b2, const float* __restrict__ bp,
    const float* __restrict__ b3, const float* __restrict__ rw,
    const int* __restrict__ cnt, const int* __restrict__ base,
    unsigned short* __restrict__ hxout, unsigned short* __restrict__ oout,
    float* __restrict__ s3) {
  __shared__ __align__(16) unsigned short As[128 * 32];
  __shared__ __align__(16) unsigned short Bs[128 * 32];

  // map blockIdx.y -> (expert, local row tile)
  int lt = blockIdx.y;
  int e = 0, cn = 0, ok = 0;
  for (e = 0; e < NEXP; ++e) {
    int c = cnt[e];
    int nt = (c + 127) >> 7;
    if (lt < nt) { cn = c; ok = 1; break; }
    lt -= nt;
  }
  if (!ok) return;
  int be = base[e];
  int row0 = lt << 7;
  int tn = blockIdx.x << 7;

  TILE_SETUP();

  int rl0 = row0 + sr, rl1 = row0 + 64 + sr;
  int cl0 = min(rl0, cn - 1), cl1 = min(rl1, cn - 1);

  if (MODE == 1) {
    const unsigned short* a0p = hx + (size_t)(be + cl0) * 3072 + 2048 + koffA;
    const unsigned short* a1p = hx + (size_t)(be + cl1) * 3072 + 2048 + koffA;
    const unsigned short* bw0 = w1t + ((size_t)e * HID + tn + sr) * DIN + koffA;
    const unsigned short* bw1 = w1t + ((size_t)e * HID + tn + 64 + sr) * DIN + koffA;
    KLOOP(a0p, a1p, bw0, bw1, DIN / 32);
  } else if (MODE == 2) {
    const unsigned short* a0p = hx + (size_t)(be + cl0) * 3072 + koffA;
    const unsigned short* a1p = hx + (size_t)(be + cl1) * 3072 + koffA;
    const unsigned short* bw0 = w2p + ((size_t)e * HID + tn + sr) * 3072 + koffA;
    const unsigned short* bw1 = w2p + ((size_t)e * HID + tn + 64 + sr) * 3072 + koffA;
    KLOOP(a0p, a1p, bw0, bw1, 3072 / 32);
  } else {
    const unsigned short* a0p = obuf + (size_t)(be + cl0) * HID + koffA;
    const unsigned short* a1p = obuf + (size_t)(be + cl1) * HID + koffA;
    const unsigned short* bw0 = w3t + ((size_t)e * DOUTN + tn + sr) * HID + koffA;
    const unsigned short* bw1 = w3t + ((size_t)e * DOUTN + tn + 64 + sr) * HID + koffA;
    KLOOP(a0p, a1p, bw0, bw1, HID / 32);
  }

  // ---- epilogue (C/D: col=lane&15, row=quad*4+reg) ----
  int crow = row0 + wm + q * 4;
  int ccol0 = tn + wn + l15;
  if (MODE == 1) {
    const float* bb = b1 + (size_t)e * HID;
#pragma unroll
    for (int ni = 0; ni < 4; ++ni) {
      int col = ccol0 + ni * 16;
      float bias = bb[col];
#pragma unroll
      for (int mi = 0; mi < 4; ++mi)
#pragma unroll
        for (int rg = 0; rg < 4; ++rg) {
          int rr = crow + mi * 16 + rg;
          if (rr < cn) {
            float v = fmaxf(acc[mi][ni][rg] + bias, 0.f);
            hxout[(size_t)(be + rr) * 3072 + col] = f2b(v);
          }
        }
    }
  } else if (MODE == 2) {
    const float* bb = b2 + (size_t)e * HID;
    const float* bq = bp + (size_t)e * HID;
#pragma unroll
    for (int ni = 0; ni < 4; ++ni) {
      int col = ccol0 + ni * 16;
      float bias = bb[col] + bq[col];
#pragma unroll
      for (int mi = 0; mi < 4; ++mi)
#pragma unroll
        for (int rg = 0; rg < 4; ++rg) {
          int rr = crow + mi * 16 + rg;
          if (rr < cn) {
            float v = fmaxf(acc[mi][ni][rg] + bias, 0.f);
            oout[(size_t)(be + rr) * HID + col] = f2b(v);
          }
        }
    }
  } else {
    const float* bb = b3 + (size_t)e * DOUTN;
    float biasv[4];
#pragma unroll
    for (int ni = 0; ni < 4; ++ni) biasv[ni] = bb[ccol0 + ni * 16];
#pragma unroll
    for (int mi = 0; mi < 4; ++mi)
#pragma unroll
      for (int rg = 0; rg < 4; ++rg) {
        int rr = crow + mi * 16 + rg;
        if (rr < cn) {
          float wgt = rw[be + rr];
#pragma unroll
          for (int ni = 0; ni < 4; ++ni) {
            int col = ccol0 + ni * 16;
            s3[(size_t)(be + rr) * DOUTN + col] =
                (acc[mi][ni][rg] + biasv[ni]) * wgt;
          }
        }
      }
  }
}

// ---------------- launch ----------------

extern "C" void kernel_launch(void* const* d_in, const int* in_sizes, int n_in,
                              void* d_out, int out_size, void* d_ws,
                              size_t ws_size, hipStream_t stream) {
  const float* x = (const float*)d_in[0];
  const float* w1 = (const float*)d_in[1];
  const float* b1 = (const float*)d_in[2];
  const float* w2 = (const float*)d_in[3];
  const float* b2 = (const float*)d_in[4];
  const float* w3 = (const float*)d_in[5];
  const float* b3 = (const float*)d_in[6];
  const float* wp = (const float*)d_in[7];
  const float* bp = (const float*)d_in[8];
  const float* gw1 = (const float*)d_in[9];
  const float* gb1 = (const float*)d_in[10];
  const float* gw2 = (const float*)d_in[11];
  const float* gb2 = (const float*)d_in[12];
  float* outp = (float*)d_out;
  char* ws = (char*)d_ws;

  // workspace layout (~325.4 MiB)
  const size_t o_w2p = 0;                                   // [E][2048][3072] bf16 = 100.7 MB
  const size_t o_w3t = o_w2p + (size_t)NEXP * HID * 3072 * 2;      // 33.5 MB
  const size_t o_xb  = o_w3t + (size_t)NEXP * DOUTN * HID * 2;     // 16.8 MB
  const size_t o_w1t = o_xb + (size_t)TOK * DIN * 2;               // 33.5 MB
  const size_t o_hg  = o_w1t + (size_t)NEXP * HID * DIN * 2;       // 33.5 MB
  const size_t o_hx  = o_hg + (size_t)TOK * GHID * 4;              // 100.7 MB
  const size_t o_gw1t3 = o_hx + (size_t)2 * TOK * 3072 * 2;        // 6.3 MB
  const size_t o_gidx = o_gw1t3 + (size_t)GHID * 3072 * 2;
  const size_t o_gw  = o_gidx + (size_t)2 * TOK * 4;
  const size_t o_cnt = o_gw + (size_t)2 * TOK * 4;
  const size_t o_base = o_cnt + 128;
  const size_t o_cur = o_base + 128;
  const size_t o_rt  = o_cur + 128;
  const size_t o_rw  = o_rt + (size_t)2 * TOK * 4;
  const size_t o_inv = o_rw + (size_t)2 * TOK * 4;
  // aliases (sequential-stream safe):
  const size_t o_xcat = o_hx;   // gating A (50 MB) in hx region; dead before xgather
  const size_t o_ob   = o_w1t;  // obuf bf16 [16384][2048] (67.1 MB) = w1t(33.5)+hg(33.5), both dead at MODE2
  const size_t o_s3   = o_w2p;  // s3 fp32 [16384][1024] (67.1 MB) in w2p region, dead at MODE3

  unsigned short* w2p = (unsigned short*)(ws + o_w2p);
  unsigned short* w3t = (unsigned short*)(ws + o_w3t);
  unsigned short* xb = (unsigned short*)(ws + o_xb);
  unsigned short* w1t = (unsigned short*)(ws + o_w1t);
  float* hg = (float*)(ws + o_hg);
  unsigned short* hx = (unsigned short*)(ws + o_hx);
  unsigned short* gw1t3 = (unsigned short*)(ws + o_gw1t3);
  unsigned short* xcat = (unsigned short*)(ws + o_xcat);
  unsigned short* obuf = (unsigned short*)(ws + o_ob);
  float* s3 = (float*)(ws + o_s3);
  int* gidx = (int*)(ws + o_gidx);
  float* gwt = (float*)(ws + o_gw);
  int* cnt = (int*)(ws + o_cnt);
  int* basep = (int*)(ws + o_base);
  int* cur = (int*)(ws + o_cur);
  int* rtl = (int*)(ws + o_rt);
  float* rwl = (float*)(ws + o_rw);
  int* invp = (int*)(ws + o_inv);

  hipMemsetAsync(ws + o_cnt, 0, 32, stream);

  cvt_x_kernel<<<dim3(TOK * DIN / 4 / 256), 256, 0, stream>>>(x, xb, xcat, TOK * DIN / 4);
  cvt_gw1_kernel<<<dim3(GHID / 32, DIN / 32), dim3(32, 8), 0, stream>>>(gw1, gw1t3);
  // w1 [E][1024][2048] -> w1t [E][2048][1024]
  cvt_transpose_v2<<<dim3(HID / 64, DIN / 64, NEXP), 256, 0, stream>>>(
      w1, w1t, HID, (long)DIN * HID, (long)HID * DIN, DIN);
  // w2 [E][2048][2048] -> w2p[:, :, 0:2048]
  cvt_transpose_v2<<<dim3(HID / 64, HID / 64, NEXP), 256, 0, stream>>>(
      w2, w2p, HID, (long)HID * HID, (long)HID * 3072, 3072);
  // wp [E][1024][2048] -> w2p[:, :, 2048:3072]
  cvt_transpose_v2<<<dim3(HID / 64, DIN / 64, NEXP), 256, 0, stream>>>(
      wp, w2p + 2048, HID, (long)DIN * HID, (long)HID * 3072, 3072);
  // w3 [E][2048][1024] -> w3t [E][1024][2048]
  cvt_transpose_v2<<<dim3(DOUTN / 64, HID / 64, NEXP), 256, 0, stream>>>(
      w3, w3t, DOUTN, (long)HID * DOUTN, (long)DOUTN * HID, HID);

  gating_mfma<<<dim3(GHID / 128, TOK / 128), 256, 0, stream>>>(xcat, gw1t3, gb1, hg);
  gating2_topk<<<dim3(TOK / 4), 256, 0, stream>>>(hg, gw2, gb2, gidx, gwt);
  route_count<<<dim3(TOK / 256), 256, 0, stream>>>(gidx, cnt);
  route_scan<<<1, 64, 0, stream>>>(cnt, basep, cur);
  route_scatter<<<dim3(TOK / 256), 256, 0, stream>>>(gidx, gwt, cur, rtl, rwl, invp);
  xgather_kernel<<<dim3(2 * TOK), 128, 0, stream>>>(xb, rtl, hx);

  moe_gemm<1><<<dim3(HID / 128, 135), 256, 0, stream>>>(
      hx, obuf, w1t, w2p, w3t, b1, b2, bp, b3, rwl, cnt, basep, hx, obuf, s3);
  moe_gemm<2><<<dim3(HID / 128, 135), 256, 0, stream>>>(
      hx, obuf, w1t, w2p, w3t, b1, b2, bp, b3, rwl, cnt, basep, hx, obuf, s3);
  moe_gemm<3><<<dim3(DOUTN / 128, 135), 256, 0, stream>>>(
      hx, obuf, w1t, w2p, w3t, b1, b2, bp, b3, rwl, cnt, basep, hx, obuf, s3);

  combine_kernel<<<dim3(TOK), 256, 0, stream>>>(s3, invp, outp);
}